// Round 1
// baseline (268.738 us; speedup 1.0000x reference)
//
#include <hip/hip_runtime.h>

// LengthRegulator: expand x (B,T,H) by per-token durations into (B,MAXLEN,H),
// plus sinusoidal positional rows per within-token offset, plus mel lengths.
// B=64, T=160, H=256, MAXLEN=2000 (fixed by the harness's setup_inputs).
constexpr int B      = 64;
constexpr int T      = 160;
constexpr int H      = 256;
constexpr int MAXLEN = 2000;
constexpr int FPB    = 16;   // frames per block (4 waves x 4 frames)
constexpr int NTH    = 256;

__global__ __launch_bounds__(NTH) void lr_kernel(
    const float* __restrict__ x,
    const float* __restrict__ pos_enc,
    const int*   __restrict__ duration,
    float*       __restrict__ out)
{
    __shared__ int s_scan[NTH];
    __shared__ int s_csum[T];
    __shared__ int s_excl[T];

    const int b   = blockIdx.y;
    const int tid = threadIdx.x;

    // --- inclusive scan of duration[b, :] (160 elems, padded to 256) ---
    int d = (tid < T) ? duration[b * T + tid] : 0;
    s_scan[tid] = d;
    __syncthreads();
    #pragma unroll
    for (int off = 1; off < NTH; off <<= 1) {
        int v   = s_scan[tid];
        int add = (tid >= off) ? s_scan[tid - off] : 0;
        __syncthreads();
        s_scan[tid] = v + add;
        __syncthreads();
    }
    if (tid < T) {
        s_csum[tid] = s_scan[tid];
        s_excl[tid] = s_scan[tid] - d;   // exclusive prefix
    }
    __syncthreads();

    const int mel_len = s_csum[T - 1];

    // mel_len output (as float32, third chunk of the flat output buffer)
    if (blockIdx.x == 0 && tid == 0) {
        out[(size_t)2 * B * MAXLEN * H + b] = (float)mel_len;
    }

    const int wave = tid >> 6;   // 0..3
    const int lane = tid & 63;   // float4 index within the 256-wide row

    const size_t out_base = (size_t)b * MAXLEN * H;
    const size_t pos_base = (size_t)B * MAXLEN * H + out_base;
    const int f0 = blockIdx.x * FPB;

    for (int i = wave; i < FPB; i += 4) {
        const int f = f0 + i;
        if (f >= MAXLEN) break;
        const bool valid = (f < mel_len);

        // upper_bound: first j with csum[j] > f  (wave-uniform -> LDS broadcast)
        int lo = 0, hi = T;
        while (lo < hi) {
            int mid = (lo + hi) >> 1;
            if (s_csum[mid] <= f) lo = mid + 1; else hi = mid;
        }
        const int idx = min(lo, T - 1);

        float4 xo = make_float4(0.f, 0.f, 0.f, 0.f);
        float4 po = xo;
        if (valid) {
            const int pw = f - s_excl[idx];              // within-token position, 0..11
            xo = ((const float4*)(x + ((size_t)b * T + idx) * H))[lane];
            po = ((const float4*)(pos_enc + (size_t)pw * H))[lane];
        }
        ((float4*)(out + out_base + (size_t)f * H))[lane] = xo;
        ((float4*)(out + pos_base + (size_t)f * H))[lane] = po;
    }
}

extern "C" void kernel_launch(void* const* d_in, const int* in_sizes, int n_in,
                              void* d_out, int out_size, void* d_ws, size_t ws_size,
                              hipStream_t stream)
{
    const float* x        = (const float*)d_in[0];
    const float* pos_enc  = (const float*)d_in[1];
    const int*   duration = (const int*)d_in[2];
    float*       out      = (float*)d_out;

    dim3 grid((MAXLEN + FPB - 1) / FPB, B);
    lr_kernel<<<grid, NTH, 0, stream>>>(x, pos_enc, duration, out);
}